// Round 3
// baseline (1219.885 us; speedup 1.0000x reference)
//
#include <hip/hip_runtime.h>
#include <hip/hip_fp16.h>
#include <cstdint>
#include <cstddef>

// MoE FFN, D=512 F=2048 E=8 K=2, N=32768 tokens. fp16 MFMA, depth-2 pipelined K-loop.
#define NTOK 32768
#define DM 512
#define FF 2048
#define NE 8

typedef _Float16 half8 __attribute__((ext_vector_type(8)));
typedef float floatx4 __attribute__((ext_vector_type(4)));

// async global->LDS, 16B per lane. LDS dest is wave-uniform base + lane*16 (HW).
__device__ __forceinline__ void async16(const void* g, void* l) {
  __builtin_amdgcn_global_load_lds(
      (const __attribute__((address_space(1))) uint32_t*)g,
      (__attribute__((address_space(3))) uint32_t*)l,
      16, 0, 0);
}

// ---------------- transpose + fp32->fp16 cast: W (E,R,C) -> Wt (E,C,R) ----------------
__global__ __launch_bounds__(256) void k_transpose(const float* __restrict__ W,
                                                   _Float16* __restrict__ Wt, int R, int C) {
  __shared__ float tile[32][33];
  int e = blockIdx.z;
  int c0 = blockIdx.x * 32, r0 = blockIdx.y * 32;
  const float* Wp = W + (size_t)e * R * C;
  _Float16* Wtp = Wt + (size_t)e * R * C;
  int tx = threadIdx.x & 31, ty = threadIdx.x >> 5;
  #pragma unroll
  for (int rr = ty; rr < 32; rr += 8)
    tile[rr][tx] = Wp[(size_t)(r0 + rr) * C + c0 + tx];
  __syncthreads();
  #pragma unroll
  for (int cc = ty; cc < 32; cc += 8)
    Wtp[(size_t)(c0 + cc) * R + r0 + tx] = (_Float16)tile[tx][cc];
}

// ---------------- router: logits, top-2, softmax weights, aux accumulators, x->f16 ----------------
__global__ __launch_bounds__(256) void k_router(
    const float* __restrict__ x, const float* __restrict__ rw,
    _Float16* __restrict__ xb, int* __restrict__ route_e, float* __restrict__ route_w,
    int* __restrict__ counts, float* __restrict__ aux_acc) {
  __shared__ float s_p[NE];
  __shared__ float s_c[NE];
  __shared__ int s_cnt[NE];
  int tid = threadIdx.x, lane = tid & 63, wave = tid >> 6;
  if (tid < NE) { s_p[tid] = 0.f; s_c[tid] = 0.f; s_cnt[tid] = 0; }
  __syncthreads();
  int n = blockIdx.x * 4 + wave;  // one wave per token
  const float4* xr = (const float4*)(x + (size_t)n * DM + lane * 8);
  float4 x0 = xr[0], x1 = xr[1];
  float xv[8] = {x0.x, x0.y, x0.z, x0.w, x1.x, x1.y, x1.z, x1.w};
  float acc[NE];
  #pragma unroll
  for (int e = 0; e < NE; e++) acc[e] = 0.f;
  const float4* rwv = (const float4*)rw;  // (D, E=8) row-major: 2 float4 per row
  #pragma unroll
  for (int j = 0; j < 8; j++) {
    int d = lane * 8 + j;
    float4 r0 = rwv[d * 2], r1 = rwv[d * 2 + 1];
    float xd = xv[j];
    acc[0] += xd * r0.x; acc[1] += xd * r0.y; acc[2] += xd * r0.z; acc[3] += xd * r0.w;
    acc[4] += xd * r1.x; acc[5] += xd * r1.y; acc[6] += xd * r1.z; acc[7] += xd * r1.w;
  }
  half8 hv;
  #pragma unroll
  for (int j = 0; j < 8; j++) hv[j] = (_Float16)xv[j];
  *(half8*)(xb + (size_t)n * DM + lane * 8) = hv;
  #pragma unroll
  for (int e = 0; e < NE; e++) {
    #pragma unroll
    for (int m = 1; m < 64; m <<= 1) acc[e] += __shfl_xor(acc[e], m);
  }
  if (lane == 0) {
    int e0 = 0; float v0 = acc[0];
    for (int e = 1; e < NE; e++) if (acc[e] > v0) { v0 = acc[e]; e0 = e; }
    int e1 = (e0 == 0) ? 1 : 0; float v1 = acc[e1];
    for (int e = 0; e < NE; e++) if (e != e0 && acc[e] > v1) { v1 = acc[e]; e1 = e; }
    float w0 = 1.f / (1.f + expf(v1 - v0));
    float w1 = 1.f - w0;
    route_e[n] = e0 | (e1 << 8);
    route_w[2 * n] = w0; route_w[2 * n + 1] = w1;
    float mx = acc[0];
    for (int e = 1; e < NE; e++) mx = fmaxf(mx, acc[e]);
    float p[NE]; float s = 0.f;
    for (int e = 0; e < NE; e++) { p[e] = expf(acc[e] - mx); s += p[e]; }
    float inv = 1.f / s;
    atomicAdd(&s_cnt[e0], 1); atomicAdd(&s_cnt[e1], 1);
    for (int e = 0; e < NE; e++) atomicAdd(&s_p[e], p[e] * inv);
    atomicAdd(&s_c[e0], 1.f);
  }
  __syncthreads();
  if (tid < NE) {
    atomicAdd(&counts[tid], s_cnt[tid]);
    atomicAdd(&aux_acc[tid], s_p[tid]);
    atomicAdd(&aux_acc[NE + tid], s_c[tid]);
  }
}

// ---------------- offsets (prefix sum over 8) + aux loss ----------------
__global__ void k_finalize(const int* __restrict__ counts, int* __restrict__ offsets,
                           int* __restrict__ cursors, const float* __restrict__ aux_acc,
                           float* __restrict__ out_aux) {
  if (threadIdx.x == 0 && blockIdx.x == 0) {
    int off = 0;
    for (int e = 0; e < NE; e++) { offsets[e] = off; cursors[e] = off; off += counts[e]; }
    const float invN = 1.f / (float)NTOK;
    float aux = 0.f;
    for (int e = 0; e < NE; e++) aux += (aux_acc[e] * invN) * (aux_acc[NE + e] * invN);
    out_aux[0] = 0.01f * (float)NE * aux;
  }
}

// ---------------- build compacted per-expert token lists ----------------
__global__ __launch_bounds__(256) void k_build(
    const int* __restrict__ route_e, const float* __restrict__ route_w,
    int* __restrict__ cursors, int* __restrict__ tok, float* __restrict__ wgt) {
  __shared__ int s_cnt[NE];
  __shared__ int s_base[NE];
  int tid = threadIdx.x;
  if (tid < NE) s_cnt[tid] = 0;
  __syncthreads();
  int n = blockIdx.x * 256 + tid;
  int re = route_e[n];
  int e0 = re & 0xff, e1 = (re >> 8) & 0xff;
  float w0 = route_w[2 * n], w1 = route_w[2 * n + 1];
  int p0 = atomicAdd(&s_cnt[e0], 1);
  int p1 = atomicAdd(&s_cnt[e1], 1);
  __syncthreads();
  if (tid < NE) s_base[tid] = atomicAdd(&cursors[tid], s_cnt[tid]);
  __syncthreads();
  int g0 = s_base[e0] + p0, g1 = s_base[e1] + p1;
  tok[g0] = n; wgt[g0] = w0;
  tok[g1] = n; wgt[g1] = w1;
}

// Pipelined K-loop shared shape: 3 LDS stages of (A 128x32 + B 128x32) fp16.
// Per iter: wait own stage-k loads (vmcnt(4): stage k+1 stays in flight) ->
// raw barrier -> issue stage k+2 -> ds_read/MFMA stage k.
// Safety: stage written at iter k was read at iter k-1; the iter-k barrier
// certifies those ds_reads completed (MFMA consumption forced lgkmcnt waits).
#define WAIT4() asm volatile("s_waitcnt vmcnt(4)" ::: "memory")
#define WAIT0() asm volatile("s_waitcnt vmcnt(0)" ::: "memory")

// ---------------- GEMM1: h[:, fbase:fbase+Fc] = gelu(Xg @ w1[e] + b1[e]), gathered rows ----------------
__global__ __launch_bounds__(256, 3) void k_ffn1(
    const _Float16* __restrict__ xb, const _Float16* __restrict__ w1t,
    const float* __restrict__ b1, const int* __restrict__ counts,
    const int* __restrict__ offsets, const int* __restrict__ tok,
    _Float16* __restrict__ h, int Fc, int fbase) {
  int e = blockIdx.z;
  int cnt = counts[e];
  int tm = blockIdx.y;
  if (tm * 128 >= cnt) return;
  int tn = blockIdx.x;
  int off = offsets[e];
  __shared__ _Float16 As[3 * 4096];
  __shared__ _Float16 Bs[3 * 4096];
  int tid = threadIdx.x, lane = tid & 63, wave = tid >> 6;
  int rowL = tid >> 2, kc = (tid & 3) * 8;
  int tr0 = tm * 128 + rowL;
  int tr1 = tr0 + 64;
  int tok0 = tok[off + (tr0 < cnt ? tr0 : 0)];
  int tok1 = tok[off + (tr1 < cnt ? tr1 : 0)];
  const _Float16* a0 = xb + (size_t)tok0 * DM + kc;
  const _Float16* a1 = xb + (size_t)tok1 * DM + kc;
  const _Float16* w1e = w1t + (size_t)e * FF * DM;  // (F, D) n-major, k contiguous
  const _Float16* bp0 = w1e + (size_t)(fbase + tn * 128 + rowL) * DM + kc;
  const _Float16* bp1 = w1e + (size_t)(fbase + tn * 128 + 64 + rowL) * DM + kc;
  floatx4 acc[4][4];
  floatx4 zero = {0.f, 0.f, 0.f, 0.f};
  #pragma unroll
  for (int i = 0; i < 4; i++)
    #pragma unroll
    for (int j = 0; j < 4; j++) acc[i][j] = zero;
  int wr = wave >> 1, wc = wave & 1;
  int fr = lane & 15, kf = (lane >> 4) * 8;
  const int niter = DM / 32;

  auto issue = [&](int k0, int s) {
    _Float16* A_s = As + s * 4096;
    _Float16* B_s = Bs + s * 4096;
    async16(a0 + k0, A_s + wave * 512);
    async16(a1 + k0, A_s + 2048 + wave * 512);
    async16(bp0 + k0, B_s + wave * 512);
    async16(bp1 + k0, B_s + 2048 + wave * 512);
  };
  issue(0, 0);
  issue(32, 1);
  for (int k = 0; k < niter; k++) {
    int s = k % 3;
    if (k + 1 < niter) WAIT4(); else WAIT0();
    __builtin_amdgcn_s_barrier();
    if (k + 2 < niter) issue((k + 2) * 32, (k + 2) % 3);
    const _Float16* Ab = As + s * 4096 + (size_t)(wr * 64 + fr) * 32 + kf;
    const _Float16* Bb = Bs + s * 4096 + (size_t)(wc * 64 + fr) * 32 + kf;
    half8 av[4], bv[4];
    #pragma unroll
    for (int i = 0; i < 4; i++) av[i] = *(const half8*)(Ab + i * 512);
    #pragma unroll
    for (int j = 0; j < 4; j++) bv[j] = *(const half8*)(Bb + j * 512);
    #pragma unroll
    for (int i = 0; i < 4; i++)
      #pragma unroll
      for (int j = 0; j < 4; j++)
        acc[i][j] = __builtin_amdgcn_mfma_f32_16x16x32_f16(av[i], bv[j], acc[i][j], 0, 0, 0);
  }
  int rq = (lane >> 4) * 4, cq = lane & 15;
  #pragma unroll
  for (int j = 0; j < 4; j++) {
    int colL = tn * 128 + wc * 64 + j * 16 + cq;
    float bb = b1[e * FF + fbase + colL];
    #pragma unroll
    for (int i = 0; i < 4; i++) {
      #pragma unroll
      for (int r = 0; r < 4; r++) {
        int row = tm * 128 + wr * 64 + i * 16 + rq + r;
        if (row < cnt) {
          float v = acc[i][j][r] + bb;
          v = 0.5f * v * (1.f + erff(v * 0.70710678118654752f));  // exact GELU
          h[(size_t)(off + row) * Fc + colL] = (_Float16)v;
        }
      }
    }
  }
}

// ---------------- GEMM2: out[tok] += w * (Hc @ w2[e][fbase:fbase+Fc, :] (+ b2 on chunk 0)) ----------------
__global__ __launch_bounds__(256, 3) void k_ffn2(
    const _Float16* __restrict__ h, const _Float16* __restrict__ w2t,
    const float* __restrict__ b2, const int* __restrict__ counts,
    const int* __restrict__ offsets, const int* __restrict__ tok,
    const float* __restrict__ wgt, float* __restrict__ out, int Fc, int fbase) {
  int e = blockIdx.z;
  int cnt = counts[e];
  int tm = blockIdx.y;
  if (tm * 128 >= cnt) return;
  int tn = blockIdx.x;
  int off = offsets[e];
  __shared__ _Float16 As[3 * 4096];
  __shared__ _Float16 Bs[3 * 4096];
  int tid = threadIdx.x, lane = tid & 63, wave = tid >> 6;
  int rowL = tid >> 2, kc = (tid & 3) * 8;
  int r0c = tm * 128 + rowL;      if (r0c >= cnt) r0c = 0;
  int r1c = tm * 128 + 64 + rowL; if (r1c >= cnt) r1c = 0;
  const _Float16* a0 = h + (size_t)(off + r0c) * Fc + kc;
  const _Float16* a1 = h + (size_t)(off + r1c) * Fc + kc;
  const _Float16* w2e = w2t + (size_t)e * DM * FF;  // (D, F) n-major, k contiguous
  const _Float16* bp0 = w2e + (size_t)(tn * 128 + rowL) * FF + fbase + kc;
  const _Float16* bp1 = w2e + (size_t)(tn * 128 + 64 + rowL) * FF + fbase + kc;
  floatx4 acc[4][4];
  floatx4 zero = {0.f, 0.f, 0.f, 0.f};
  #pragma unroll
  for (int i = 0; i < 4; i++)
    #pragma unroll
    for (int j = 0; j < 4; j++) acc[i][j] = zero;
  int wr = wave >> 1, wc = wave & 1;
  int fr = lane & 15, kf = (lane >> 4) * 8;
  const int niter = Fc / 32;

  auto issue = [&](int k0, int s) {
    _Float16* A_s = As + s * 4096;
    _Float16* B_s = Bs + s * 4096;
    async16(a0 + k0, A_s + wave * 512);
    async16(a1 + k0, A_s + 2048 + wave * 512);
    async16(bp0 + k0, B_s + wave * 512);
    async16(bp1 + k0, B_s + 2048 + wave * 512);
  };
  issue(0, 0);
  issue(32, 1);
  for (int k = 0; k < niter; k++) {
    int s = k % 3;
    if (k + 1 < niter) WAIT4(); else WAIT0();
    __builtin_amdgcn_s_barrier();
    if (k + 2 < niter) issue((k + 2) * 32, (k + 2) % 3);
    const _Float16* Ab = As + s * 4096 + (size_t)(wr * 64 + fr) * 32 + kf;
    const _Float16* Bb = Bs + s * 4096 + (size_t)(wc * 64 + fr) * 32 + kf;
    half8 av[4], bv[4];
    #pragma unroll
    for (int i = 0; i < 4; i++) av[i] = *(const half8*)(Ab + i * 512);
    #pragma unroll
    for (int j = 0; j < 4; j++) bv[j] = *(const half8*)(Bb + j * 512);
    #pragma unroll
    for (int i = 0; i < 4; i++)
      #pragma unroll
      for (int j = 0; j < 4; j++)
        acc[i][j] = __builtin_amdgcn_mfma_f32_16x16x32_f16(av[i], bv[j], acc[i][j], 0, 0, 0);
  }
  int rq = (lane >> 4) * 4, cq = lane & 15;
  int addb = (fbase == 0) ? 1 : 0;
  #pragma unroll
  for (int j = 0; j < 4; j++) {
    int col = tn * 128 + wc * 64 + j * 16 + cq;
    float bb = addb ? b2[e * DM + col] : 0.f;
    #pragma unroll
    for (int i = 0; i < 4; i++) {
      #pragma unroll
      for (int r = 0; r < 4; r++) {
        int row = tm * 128 + wr * 64 + i * 16 + rq + r;
        if (row < cnt) {
          int t = tok[off + row];
          float w = wgt[off + row];
          atomicAdd(&out[(size_t)t * DM + col], w * (acc[i][j][r] + bb));
        }
      }
    }
  }
}

extern "C" void kernel_launch(void* const* d_in, const int* in_sizes, int n_in,
                              void* d_out, int out_size, void* d_ws, size_t ws_size,
                              hipStream_t stream) {
  const float* x  = (const float*)d_in[0];
  const float* rw = (const float*)d_in[1];
  const float* w1 = (const float*)d_in[2];
  const float* b1 = (const float*)d_in[3];
  const float* w2 = (const float*)d_in[4];
  const float* b2 = (const float*)d_in[5];
  float* out = (float*)d_out;

  uint8_t* ws = (uint8_t*)d_ws;
  _Float16* xb  = (_Float16*)ws;  ws += (size_t)NTOK * DM * 2;       // 33.5 MB
  _Float16* w1t = (_Float16*)ws;  ws += (size_t)NE * FF * DM * 2;    // 16.8 MB
  _Float16* w2t = (_Float16*)ws;  ws += (size_t)NE * DM * FF * 2;    // 16.8 MB
  int*   tok     = (int*)ws;      ws += (size_t)2 * NTOK * 4;
  float* wgt     = (float*)ws;    ws += (size_t)2 * NTOK * 4;
  int*   route_e = (int*)ws;      ws += (size_t)NTOK * 4;
  float* route_w = (float*)ws;    ws += (size_t)NTOK * 8;
  int*   counts  = (int*)ws;      ws += 8 * 4;
  int*   offsets = (int*)ws;      ws += 8 * 4;
  int*   cursors = (int*)ws;      ws += 8 * 4;
  float* aux     = (float*)ws;    ws += 16 * 4;
  _Float16* h   = (_Float16*)ws;  // K-chunked h buffer: 2*NTOK rows x Fc cols

  size_t fixed = (size_t)(ws - (uint8_t*)d_ws);
  int Fc = FF;  // largest F-chunk that fits the workspace
  while (Fc > 128 && fixed + (size_t)2 * NTOK * (size_t)Fc * 2 > ws_size) Fc >>= 1;
  int NC = FF / Fc;

  hipMemsetAsync(d_out, 0, (size_t)out_size * 4, stream);           // scatter-add target
  hipMemsetAsync(counts, 0, (8 + 8 + 8 + 16) * 4, stream);          // counts..aux

  k_transpose<<<dim3(FF / 32, DM / 32, NE), 256, 0, stream>>>(w1, w1t, DM, FF);
  k_transpose<<<dim3(DM / 32, FF / 32, NE), 256, 0, stream>>>(w2, w2t, FF, DM);
  k_router<<<NTOK / 4, 256, 0, stream>>>(x, rw, xb, route_e, route_w, counts, aux);
  k_finalize<<<1, 64, 0, stream>>>(counts, offsets, cursors, aux, out + (size_t)NTOK * DM);
  k_build<<<NTOK / 256, 256, 0, stream>>>(route_e, route_w, cursors, tok, wgt);
  for (int c = 0; c < NC; c++) {
    k_ffn1<<<dim3(Fc / 128, NTOK / 128, NE), 256, 0, stream>>>(
        xb, w1t, b1, counts, offsets, tok, h, Fc, c * Fc);
    k_ffn2<<<dim3(DM / 128, NTOK / 128, NE), 256, 0, stream>>>(
        h, w2t, b2, counts, offsets, tok, wgt, out, Fc, c * Fc);
  }
}

// Round 4
// 1150.113 us; speedup vs baseline: 1.0607x; 1.0607x over previous
//
#include <hip/hip_runtime.h>
#include <hip/hip_fp16.h>
#include <cstdint>
#include <cstddef>

// MoE FFN, D=512 F=2048 E=8 K=2, N=32768 tokens. fp16 MFMA.
// K-loop: register-prefetch pipeline (global->VGPR->ds_write, double-buffered LDS,
// raw s_barrier so in-flight global loads are NOT drained at the barrier).
#define NTOK 32768
#define DM 512
#define FF 2048
#define NE 8

typedef _Float16 half8 __attribute__((ext_vector_type(8)));
typedef float floatx4 __attribute__((ext_vector_type(4)));

#define LGKM0_BARRIER() do { \
  asm volatile("s_waitcnt lgkmcnt(0)" ::: "memory"); \
  __builtin_amdgcn_s_barrier(); \
} while (0)

// ---------------- transpose + fp32->fp16 cast: W (E,R,C) -> Wt (E,C,R) ----------------
__global__ __launch_bounds__(256) void k_transpose(const float* __restrict__ W,
                                                   _Float16* __restrict__ Wt, int R, int C) {
  __shared__ float tile[32][33];
  int e = blockIdx.z;
  int c0 = blockIdx.x * 32, r0 = blockIdx.y * 32;
  const float* Wp = W + (size_t)e * R * C;
  _Float16* Wtp = Wt + (size_t)e * R * C;
  int tx = threadIdx.x & 31, ty = threadIdx.x >> 5;
  #pragma unroll
  for (int rr = ty; rr < 32; rr += 8)
    tile[rr][tx] = Wp[(size_t)(r0 + rr) * C + c0 + tx];
  __syncthreads();
  #pragma unroll
  for (int cc = ty; cc < 32; cc += 8)
    Wtp[(size_t)(c0 + cc) * R + r0 + tx] = (_Float16)tile[tx][cc];
}

// ---------------- router: logits, top-2, softmax weights, aux accumulators, x->f16 ----------------
__global__ __launch_bounds__(256) void k_router(
    const float* __restrict__ x, const float* __restrict__ rw,
    _Float16* __restrict__ xb, int* __restrict__ route_e, float* __restrict__ route_w,
    int* __restrict__ counts, float* __restrict__ aux_acc) {
  __shared__ float s_p[NE];
  __shared__ float s_c[NE];
  __shared__ int s_cnt[NE];
  int tid = threadIdx.x, lane = tid & 63, wave = tid >> 6;
  if (tid < NE) { s_p[tid] = 0.f; s_c[tid] = 0.f; s_cnt[tid] = 0; }
  __syncthreads();
  int n = blockIdx.x * 4 + wave;  // one wave per token
  const float4* xr = (const float4*)(x + (size_t)n * DM + lane * 8);
  float4 x0 = xr[0], x1 = xr[1];
  float xv[8] = {x0.x, x0.y, x0.z, x0.w, x1.x, x1.y, x1.z, x1.w};
  float acc[NE];
  #pragma unroll
  for (int e = 0; e < NE; e++) acc[e] = 0.f;
  const float4* rwv = (const float4*)rw;  // (D, E=8) row-major: 2 float4 per row
  #pragma unroll
  for (int j = 0; j < 8; j++) {
    int d = lane * 8 + j;
    float4 r0 = rwv[d * 2], r1 = rwv[d * 2 + 1];
    float xd = xv[j];
    acc[0] += xd * r0.x; acc[1] += xd * r0.y; acc[2] += xd * r0.z; acc[3] += xd * r0.w;
    acc[4] += xd * r1.x; acc[5] += xd * r1.y; acc[6] += xd * r1.z; acc[7] += xd * r1.w;
  }
  half8 hv;
  #pragma unroll
  for (int j = 0; j < 8; j++) hv[j] = (_Float16)xv[j];
  *(half8*)(xb + (size_t)n * DM + lane * 8) = hv;
  #pragma unroll
  for (int e = 0; e < NE; e++) {
    #pragma unroll
    for (int m = 1; m < 64; m <<= 1) acc[e] += __shfl_xor(acc[e], m);
  }
  if (lane == 0) {
    int e0 = 0; float v0 = acc[0];
    for (int e = 1; e < NE; e++) if (acc[e] > v0) { v0 = acc[e]; e0 = e; }
    int e1 = (e0 == 0) ? 1 : 0; float v1 = acc[e1];
    for (int e = 0; e < NE; e++) if (e != e0 && acc[e] > v1) { v1 = acc[e]; e1 = e; }
    float w0 = 1.f / (1.f + expf(v1 - v0));
    float w1 = 1.f - w0;
    route_e[n] = e0 | (e1 << 8);
    route_w[2 * n] = w0; route_w[2 * n + 1] = w1;
    float mx = acc[0];
    for (int e = 1; e < NE; e++) mx = fmaxf(mx, acc[e]);
    float p[NE]; float s = 0.f;
    for (int e = 0; e < NE; e++) { p[e] = expf(acc[e] - mx); s += p[e]; }
    float inv = 1.f / s;
    atomicAdd(&s_cnt[e0], 1); atomicAdd(&s_cnt[e1], 1);
    for (int e = 0; e < NE; e++) atomicAdd(&s_p[e], p[e] * inv);
    atomicAdd(&s_c[e0], 1.f);
  }
  __syncthreads();
  if (tid < NE) {
    atomicAdd(&counts[tid], s_cnt[tid]);
    atomicAdd(&aux_acc[tid], s_p[tid]);
    atomicAdd(&aux_acc[NE + tid], s_c[tid]);
  }
}

// ---------------- offsets (prefix sum over 8) + aux loss ----------------
__global__ void k_finalize(const int* __restrict__ counts, int* __restrict__ offsets,
                           int* __restrict__ cursors, const float* __restrict__ aux_acc,
                           float* __restrict__ out_aux) {
  if (threadIdx.x == 0 && blockIdx.x == 0) {
    int off = 0;
    for (int e = 0; e < NE; e++) { offsets[e] = off; cursors[e] = off; off += counts[e]; }
    const float invN = 1.f / (float)NTOK;
    float aux = 0.f;
    for (int e = 0; e < NE; e++) aux += (aux_acc[e] * invN) * (aux_acc[NE + e] * invN);
    out_aux[0] = 0.01f * (float)NE * aux;
  }
}

// ---------------- build compacted per-expert token lists ----------------
__global__ __launch_bounds__(256) void k_build(
    const int* __restrict__ route_e, const float* __restrict__ route_w,
    int* __restrict__ cursors, int* __restrict__ tok, float* __restrict__ wgt) {
  __shared__ int s_cnt[NE];
  __shared__ int s_base[NE];
  int tid = threadIdx.x;
  if (tid < NE) s_cnt[tid] = 0;
  __syncthreads();
  int n = blockIdx.x * 256 + tid;
  int re = route_e[n];
  int e0 = re & 0xff, e1 = (re >> 8) & 0xff;
  float w0 = route_w[2 * n], w1 = route_w[2 * n + 1];
  int p0 = atomicAdd(&s_cnt[e0], 1);
  int p1 = atomicAdd(&s_cnt[e1], 1);
  __syncthreads();
  if (tid < NE) s_base[tid] = atomicAdd(&cursors[tid], s_cnt[tid]);
  __syncthreads();
  int g0 = s_base[e0] + p0, g1 = s_base[e1] + p1;
  tok[g0] = n; wgt[g0] = w0;
  tok[g1] = n; wgt[g1] = w1;
}

// ---------------- GEMM1: h[:, fbase:fbase+Fc] = gelu(Xg @ w1[e] + b1[e]), gathered rows ----------------
// 128x128 tile, BK=32, 4 waves x (4x4) 16x16x32 f16 MFMA; register-prefetch double-buffer.
__global__ __launch_bounds__(256, 3) void k_ffn1(
    const _Float16* __restrict__ xb, const _Float16* __restrict__ w1t,
    const float* __restrict__ b1, const int* __restrict__ counts,
    const int* __restrict__ offsets, const int* __restrict__ tok,
    _Float16* __restrict__ h, int Fc, int fbase) {
  int e = blockIdx.z;
  int cnt = counts[e];
  int tm = blockIdx.y;
  if (tm * 128 >= cnt) return;
  int tn = blockIdx.x;
  int off = offsets[e];
  __shared__ _Float16 As[2 * 4096];
  __shared__ _Float16 Bs[2 * 4096];
  int tid = threadIdx.x, lane = tid & 63, wave = tid >> 6;
  int rowL = tid >> 2, kc = (tid & 3) * 8;
  int tr0 = tm * 128 + rowL;
  int tr1 = tr0 + 64;
  int tok0 = tok[off + (tr0 < cnt ? tr0 : 0)];
  int tok1 = tok[off + (tr1 < cnt ? tr1 : 0)];
  const _Float16* a0 = xb + (size_t)tok0 * DM + kc;
  const _Float16* a1 = xb + (size_t)tok1 * DM + kc;
  const _Float16* w1e = w1t + (size_t)e * FF * DM;  // (F, D) n-major, k contiguous
  const _Float16* bp0 = w1e + (size_t)(fbase + tn * 128 + rowL) * DM + kc;
  const _Float16* bp1 = w1e + (size_t)(fbase + tn * 128 + 64 + rowL) * DM + kc;
  floatx4 acc[4][4];
  floatx4 zero = {0.f, 0.f, 0.f, 0.f};
  #pragma unroll
  for (int i = 0; i < 4; i++)
    #pragma unroll
    for (int j = 0; j < 4; j++) acc[i][j] = zero;
  int wr = wave >> 1, wc = wave & 1;
  int fr = lane & 15, kf = (lane >> 4) * 8;
  const int niter = DM / 32;
  int wa = rowL * 32 + kc;          // LDS write addr, rows 0..63
  int wa2 = (64 + rowL) * 32 + kc;  // rows 64..127

  half8 ra0 = *(const half8*)(a0);
  half8 ra1 = *(const half8*)(a1);
  half8 rb0 = *(const half8*)(bp0);
  half8 rb1 = *(const half8*)(bp1);
  *(half8*)(As + wa) = ra0;
  *(half8*)(As + wa2) = ra1;
  *(half8*)(Bs + wa) = rb0;
  *(half8*)(Bs + wa2) = rb1;
  ra0 = *(const half8*)(a0 + 32);
  ra1 = *(const half8*)(a1 + 32);
  rb0 = *(const half8*)(bp0 + 32);
  rb1 = *(const half8*)(bp1 + 32);
  LGKM0_BARRIER();
  for (int k = 0; k < niter; k++) {
    int cur = (k & 1) * 4096, nxt = cur ^ 4096;
    if (k + 1 < niter) {
      *(half8*)(As + nxt + wa) = ra0;
      *(half8*)(As + nxt + wa2) = ra1;
      *(half8*)(Bs + nxt + wa) = rb0;
      *(half8*)(Bs + nxt + wa2) = rb1;
    }
    if (k + 2 < niter) {
      int k0 = (k + 2) * 32;
      ra0 = *(const half8*)(a0 + k0);
      ra1 = *(const half8*)(a1 + k0);
      rb0 = *(const half8*)(bp0 + k0);
      rb1 = *(const half8*)(bp1 + k0);
    }
    const _Float16* Ab = As + cur + (wr * 64 + fr) * 32 + kf;
    const _Float16* Bb = Bs + cur + (wc * 64 + fr) * 32 + kf;
    half8 av[4], bv[4];
    #pragma unroll
    for (int i = 0; i < 4; i++) av[i] = *(const half8*)(Ab + i * 512);
    #pragma unroll
    for (int j = 0; j < 4; j++) bv[j] = *(const half8*)(Bb + j * 512);
    #pragma unroll
    for (int i = 0; i < 4; i++)
      #pragma unroll
      for (int j = 0; j < 4; j++)
        acc[i][j] = __builtin_amdgcn_mfma_f32_16x16x32_f16(av[i], bv[j], acc[i][j], 0, 0, 0);
    if (k + 1 < niter) LGKM0_BARRIER();
  }
  int rq = (lane >> 4) * 4, cq = lane & 15;
  #pragma unroll
  for (int j = 0; j < 4; j++) {
    int colL = tn * 128 + wc * 64 + j * 16 + cq;
    float bb = b1[e * FF + fbase + colL];
    #pragma unroll
    for (int i = 0; i < 4; i++) {
      #pragma unroll
      for (int r = 0; r < 4; r++) {
        int row = tm * 128 + wr * 64 + i * 16 + rq + r;
        if (row < cnt) {
          float v = acc[i][j][r] + bb;
          v = 0.5f * v * (1.f + erff(v * 0.70710678118654752f));  // exact GELU
          h[(size_t)(off + row) * Fc + colL] = (_Float16)v;
        }
      }
    }
  }
}

// ---------------- GEMM2: out[tok] += w * (Hc @ w2[e][fbase:fbase+Fc, :] (+ b2 on chunk 0)) ----------------
__global__ __launch_bounds__(256, 3) void k_ffn2(
    const _Float16* __restrict__ h, const _Float16* __restrict__ w2t,
    const float* __restrict__ b2, const int* __restrict__ counts,
    const int* __restrict__ offsets, const int* __restrict__ tok,
    const float* __restrict__ wgt, float* __restrict__ out, int Fc, int fbase) {
  int e = blockIdx.z;
  int cnt = counts[e];
  int tm = blockIdx.y;
  if (tm * 128 >= cnt) return;
  int tn = blockIdx.x;
  int off = offsets[e];
  __shared__ _Float16 As[2 * 4096];
  __shared__ _Float16 Bs[2 * 4096];
  int tid = threadIdx.x, lane = tid & 63, wave = tid >> 6;
  int rowL = tid >> 2, kc = (tid & 3) * 8;
  int r0c = tm * 128 + rowL;      if (r0c >= cnt) r0c = 0;
  int r1c = tm * 128 + 64 + rowL; if (r1c >= cnt) r1c = 0;
  const _Float16* a0 = h + (size_t)(off + r0c) * Fc + kc;
  const _Float16* a1 = h + (size_t)(off + r1c) * Fc + kc;
  const _Float16* w2e = w2t + (size_t)e * DM * FF;  // (D, F) n-major, k contiguous
  const _Float16* bp0 = w2e + (size_t)(tn * 128 + rowL) * FF + fbase + kc;
  const _Float16* bp1 = w2e + (size_t)(tn * 128 + 64 + rowL) * FF + fbase + kc;
  floatx4 acc[4][4];
  floatx4 zero = {0.f, 0.f, 0.f, 0.f};
  #pragma unroll
  for (int i = 0; i < 4; i++)
    #pragma unroll
    for (int j = 0; j < 4; j++) acc[i][j] = zero;
  int wr = wave >> 1, wc = wave & 1;
  int fr = lane & 15, kf = (lane >> 4) * 8;
  const int niter = Fc / 32;
  int wa = rowL * 32 + kc;
  int wa2 = (64 + rowL) * 32 + kc;

  half8 ra0 = *(const half8*)(a0);
  half8 ra1 = *(const half8*)(a1);
  half8 rb0 = *(const half8*)(bp0);
  half8 rb1 = *(const half8*)(bp1);
  *(half8*)(As + wa) = ra0;
  *(half8*)(As + wa2) = ra1;
  *(half8*)(Bs + wa) = rb0;
  *(half8*)(Bs + wa2) = rb1;
  ra0 = *(const half8*)(a0 + 32);
  ra1 = *(const half8*)(a1 + 32);
  rb0 = *(const half8*)(bp0 + 32);
  rb1 = *(const half8*)(bp1 + 32);
  LGKM0_BARRIER();
  for (int k = 0; k < niter; k++) {
    int cur = (k & 1) * 4096, nxt = cur ^ 4096;
    if (k + 1 < niter) {
      *(half8*)(As + nxt + wa) = ra0;
      *(half8*)(As + nxt + wa2) = ra1;
      *(half8*)(Bs + nxt + wa) = rb0;
      *(half8*)(Bs + nxt + wa2) = rb1;
    }
    if (k + 2 < niter) {
      int k0 = (k + 2) * 32;
      ra0 = *(const half8*)(a0 + k0);
      ra1 = *(const half8*)(a1 + k0);
      rb0 = *(const half8*)(bp0 + k0);
      rb1 = *(const half8*)(bp1 + k0);
    }
    const _Float16* Ab = As + cur + (wr * 64 + fr) * 32 + kf;
    const _Float16* Bb = Bs + cur + (wc * 64 + fr) * 32 + kf;
    half8 av[4], bv[4];
    #pragma unroll
    for (int i = 0; i < 4; i++) av[i] = *(const half8*)(Ab + i * 512);
    #pragma unroll
    for (int j = 0; j < 4; j++) bv[j] = *(const half8*)(Bb + j * 512);
    #pragma unroll
    for (int i = 0; i < 4; i++)
      #pragma unroll
      for (int j = 0; j < 4; j++)
        acc[i][j] = __builtin_amdgcn_mfma_f32_16x16x32_f16(av[i], bv[j], acc[i][j], 0, 0, 0);
    if (k + 1 < niter) LGKM0_BARRIER();
  }
  int rq = (lane >> 4) * 4, cq = lane & 15;
  int addb = (fbase == 0) ? 1 : 0;
  #pragma unroll
  for (int j = 0; j < 4; j++) {
    int col = tn * 128 + wc * 64 + j * 16 + cq;
    float bb = addb ? b2[e * DM + col] : 0.f;
    #pragma unroll
    for (int i = 0; i < 4; i++) {
      #pragma unroll
      for (int r = 0; r < 4; r++) {
        int row = tm * 128 + wr * 64 + i * 16 + rq + r;
        if (row < cnt) {
          int t = tok[off + row];
          float w = wgt[off + row];
          atomicAdd(&out[(size_t)t * DM + col], w * (acc[i][j][r] + bb));
        }
      }
    }
  }
}

extern "C" void kernel_launch(void* const* d_in, const int* in_sizes, int n_in,
                              void* d_out, int out_size, void* d_ws, size_t ws_size,
                              hipStream_t stream) {
  const float* x  = (const float*)d_in[0];
  const float* rw = (const float*)d_in[1];
  const float* w1 = (const float*)d_in[2];
  const float* b1 = (const float*)d_in[3];
  const float* w2 = (const float*)d_in[4];
  const float* b2 = (const float*)d_in[5];
  float* out = (float*)d_out;

  uint8_t* ws = (uint8_t*)d_ws;
  _Float16* xb  = (_Float16*)ws;  ws += (size_t)NTOK * DM * 2;       // 33.5 MB
  _Float16* w1t = (_Float16*)ws;  ws += (size_t)NE * FF * DM * 2;    // 16.8 MB
  _Float16* w2t = (_Float16*)ws;  ws += (size_t)NE * DM * FF * 2;    // 16.8 MB
  int*   tok     = (int*)ws;      ws += (size_t)2 * NTOK * 4;
  float* wgt     = (float*)ws;    ws += (size_t)2 * NTOK * 4;
  int*   route_e = (int*)ws;      ws += (size_t)NTOK * 4;
  float* route_w = (float*)ws;    ws += (size_t)NTOK * 8;
  int*   counts  = (int*)ws;      ws += 8 * 4;
  int*   offsets = (int*)ws;      ws += 8 * 4;
  int*   cursors = (int*)ws;      ws += 8 * 4;
  float* aux     = (float*)ws;    ws += 16 * 4;
  _Float16* h   = (_Float16*)ws;  // K-chunked h buffer: 2*NTOK rows x Fc cols

  size_t fixed = (size_t)(ws - (uint8_t*)d_ws);
  int Fc = FF;  // largest F-chunk that fits the workspace
  while (Fc > 128 && fixed + (size_t)2 * NTOK * (size_t)Fc * 2 > ws_size) Fc >>= 1;
  int NC = FF / Fc;

  hipMemsetAsync(d_out, 0, (size_t)out_size * 4, stream);           // scatter-add target
  hipMemsetAsync(counts, 0, (8 + 8 + 8 + 16) * 4, stream);          // counts..aux

  k_transpose<<<dim3(FF / 32, DM / 32, NE), 256, 0, stream>>>(w1, w1t, DM, FF);
  k_transpose<<<dim3(DM / 32, FF / 32, NE), 256, 0, stream>>>(w2, w2t, FF, DM);
  k_router<<<NTOK / 4, 256, 0, stream>>>(x, rw, xb, route_e, route_w, counts, aux);
  k_finalize<<<1, 64, 0, stream>>>(counts, offsets, cursors, aux, out + (size_t)NTOK * DM);
  k_build<<<NTOK / 256, 256, 0, stream>>>(route_e, route_w, cursors, tok, wgt);
  for (int c = 0; c < NC; c++) {
    k_ffn1<<<dim3(Fc / 128, NTOK / 128, NE), 256, 0, stream>>>(
        xb, w1t, b1, counts, offsets, tok, h, Fc, c * Fc);
    k_ffn2<<<dim3(DM / 128, NTOK / 128, NE), 256, 0, stream>>>(
        h, w2t, b2, counts, offsets, tok, wgt, out, Fc, c * Fc);
  }
}